// Round 1
// baseline (336.443 us; speedup 1.0000x reference)
//
#include <hip/hip_runtime.h>
#include <math.h>

#define IMG_H 512
#define IMG_W 512
#define KW 11
#define RAD 5
#define T 4                 // output rows per thread (was 8)
#define NG (IMG_W / 4)      // 128 float4 column-groups per row

#define C1F (0.01f * 0.01f)
#define C2F (0.03f * 0.03f)

__device__ __forceinline__ float ssim_px(float mu1, float mu2, float sp) {
    float m12 = mu1 * mu2;
    float sigma = sp - m12;
    float sq = mu1 * mu1 + mu2 * mu2;
    return ((2.f * m12 + C1F) * (2.f * sigma + C2F)) / ((sq + C1F) * (sq + C2F));
}

// Each thread: 4 cols (one float4 group) x 4 output rows, all in registers.
// Block: 256 threads = 128 col-groups x 2 row-chunks -> covers 512 wide x 8 rows.
// Grid: (64 row-blocks, 32 images) = 2048 blocks -> 8 blocks/CU (was 4).
// launch_bounds(256,5): cap VGPR ~102 -> 5 waves/SIMD resident.
__global__ __launch_bounds__(256, 5)
void ssim_fused_kernel(const float* __restrict__ A, const float* __restrict__ B,
                       float* __restrict__ out, float inv_total) {
    __shared__ float wpart[4];

    const int tid = threadIdx.x;
    const int g = tid & (NG - 1);        // col-group 0..127
    const int rchunk = tid >> 7;         // 0..1 (wave-uniform: waves 0,1 vs 2,3)
    const int img = blockIdx.y;
    const int ybase = blockIdx.x * (2 * T) + rchunk * T;   // first output row

    // Gaussian weights (sigma=1.5, K=11) — same fp32 recipe that matched np
    // bit-exactly in earlier rounds. Forced into SGPRs (wave-uniform).
    float w[KW];
    {
        float s = 0.f;
#pragma unroll
        for (int i = 0; i < KW; ++i) {
            float d = (float)(i - RAD);
            w[i] = expf(-(d * d) / 4.5f);
            s += w[i];
        }
        float inv = 1.0f / s;
#pragma unroll
        for (int i = 0; i < KW; ++i) {
            w[i] *= inv;
            w[i] = __int_as_float(__builtin_amdgcn_readfirstlane(__float_as_int(w[i])));
        }
    }

    const float* __restrict__ Ai = A + (size_t)img * IMG_H * IMG_W;
    const float* __restrict__ Bi = B + (size_t)img * IMG_H * IMG_W;

    float4 accA[T], accB[T], accP[T];
#pragma unroll
    for (int o = 0; o < T; ++o) {
        accA[o] = make_float4(0.f, 0.f, 0.f, 0.f);
        accB[o] = accA[o];
        accP[o] = accA[o];
    }

    // Walk T + 2*RAD = 14 input rows; h-conv each, scatter into vertical accs.
#pragma unroll
    for (int i = 0; i < T + 2 * RAD; ++i) {
        int gy = ybase + i - RAD;
        if (gy >= 0 && gy < IMG_H) {     // wave-uniform branch (cheap s_cbranch)
            const float* rowA = Ai + (size_t)gy * IMG_W;
            const float* rowB = Bi + (size_t)gy * IMG_W;

            // Need cols 4g-5 .. 4g+8 (14 floats): 1 scalar + 3 float4 + 1 scalar.
            // fa[j] = col (4g-5+j).
            float fa[14], fb[14];
            {
                int c = 4 * g - 5;
                bool v = (c >= 0);
                fa[0] = v ? rowA[c] : 0.f;
                fb[0] = v ? rowB[c] : 0.f;
            }
            {   // group g-1: cols 4g-4..4g-1 (invalid only for g==0)
                float4 va = make_float4(0.f, 0.f, 0.f, 0.f);
                float4 vb = va;
                if (g >= 1) {
                    va = *(const float4*)(rowA + 4 * (g - 1));
                    vb = *(const float4*)(rowB + 4 * (g - 1));
                }
                fa[1] = va.x; fa[2] = va.y; fa[3] = va.z; fa[4] = va.w;
                fb[1] = vb.x; fb[2] = vb.y; fb[3] = vb.z; fb[4] = vb.w;
            }
            {   // group g: always valid
                float4 va = *(const float4*)(rowA + 4 * g);
                float4 vb = *(const float4*)(rowB + 4 * g);
                fa[5] = va.x; fa[6] = va.y; fa[7] = va.z; fa[8] = va.w;
                fb[5] = vb.x; fb[6] = vb.y; fb[7] = vb.z; fb[8] = vb.w;
            }
            {   // group g+1: cols 4g+4..4g+7 (invalid only for g==127)
                float4 va = make_float4(0.f, 0.f, 0.f, 0.f);
                float4 vb = va;
                if (g <= NG - 2) {
                    va = *(const float4*)(rowA + 4 * (g + 1));
                    vb = *(const float4*)(rowB + 4 * (g + 1));
                }
                fa[9]  = va.x; fa[10] = va.y; fa[11] = va.z; fa[12] = va.w;
                fb[9]  = vb.x; fb[10] = vb.y; fb[11] = vb.z; fb[12] = vb.w;
            }
            {
                int c = 4 * g + 8;
                bool v = (c < IMG_W);
                fa[13] = v ? rowA[c] : 0.f;
                fb[13] = v ? rowB[c] : 0.f;
            }

            // Shared A*B products (CSE across the 4 output columns).
            float p[14];
#pragma unroll
            for (int j = 0; j < 14; ++j) p[j] = fa[j] * fb[j];

            // Horizontal 11-tap conv: output col c uses index c+k, k=0..10.
            float4 hA = make_float4(0.f, 0.f, 0.f, 0.f);
            float4 hB = hA, hP = hA;
#pragma unroll
            for (int k = 0; k < KW; ++k) {
                float wk = w[k];
                hA.x += wk * fa[k];     hA.y += wk * fa[k + 1];
                hA.z += wk * fa[k + 2]; hA.w += wk * fa[k + 3];
                hB.x += wk * fb[k];     hB.y += wk * fb[k + 1];
                hB.z += wk * fb[k + 2]; hB.w += wk * fb[k + 3];
                hP.x += wk * p[k];      hP.y += wk * p[k + 1];
                hP.z += wk * p[k + 2];  hP.w += wk * p[k + 3];
            }

            // Vertical scatter: output o gets weight w[i-o] when 0 <= i-o <= 10.
#pragma unroll
            for (int o = 0; o < T; ++o) {
                if (i - o >= 0 && i - o < KW) {
                    float wk = w[i - o];
                    accA[o].x += wk * hA.x; accA[o].y += wk * hA.y;
                    accA[o].z += wk * hA.z; accA[o].w += wk * hA.w;
                    accB[o].x += wk * hB.x; accB[o].y += wk * hB.y;
                    accB[o].z += wk * hB.z; accB[o].w += wk * hB.w;
                    accP[o].x += wk * hP.x; accP[o].y += wk * hP.y;
                    accP[o].z += wk * hP.z; accP[o].w += wk * hP.w;
                }
            }
        }
    }

    // SSIM formula per pixel + per-thread accumulate (16 px/thread).
    float acc = 0.f;
#pragma unroll
    for (int o = 0; o < T; ++o) {
        acc += ssim_px(accA[o].x, accB[o].x, accP[o].x);
        acc += ssim_px(accA[o].y, accB[o].y, accP[o].y);
        acc += ssim_px(accA[o].z, accB[o].z, accP[o].z);
        acc += ssim_px(accA[o].w, accB[o].w, accP[o].w);
    }

    // Reduce: wave shuffle -> LDS -> one atomic per block.
#pragma unroll
    for (int off = 32; off > 0; off >>= 1)
        acc += __shfl_down(acc, off, 64);
    int wid = tid >> 6;
    int lane = tid & 63;
    if (lane == 0) wpart[wid] = acc;
    __syncthreads();
    if (tid == 0) {
        float s = (wpart[0] + wpart[1]) + (wpart[2] + wpart[3]);
        atomicAdd(out, s * inv_total);
    }
}

extern "C" void kernel_launch(void* const* d_in, const int* in_sizes, int n_in,
                              void* d_out, int out_size, void* d_ws, size_t ws_size,
                              hipStream_t stream) {
    const float* A = (const float*)d_in[0];
    const float* B = (const float*)d_in[1];
    float* out = (float*)d_out;

    const int total = in_sizes[0];                 // 32*1*512*512
    const int nimg = total / (IMG_H * IMG_W);      // 32

    hipMemsetAsync(d_out, 0, sizeof(float), stream);

    dim3 grid(IMG_H / (2 * T), nimg, 1);           // (64, 32)
    ssim_fused_kernel<<<grid, 256, 0, stream>>>(A, B, out, 1.0f / (float)total);
}

// Round 2
// 152.849 us; speedup vs baseline: 2.2011x; 2.2011x over previous
//
#include <hip/hip_runtime.h>
#include <math.h>

#define IMG_H 512
#define IMG_W 512
#define KW 11
#define RAD 5
#define T 4                 // output rows per thread
#define NG (IMG_W / 4)      // 128 float4 column-groups per row

#define C1F (0.01f * 0.01f)
#define C2F (0.03f * 0.03f)

__device__ __forceinline__ float ssim_px(float mu1, float mu2, float sp) {
    float m12 = mu1 * mu2;
    float sigma = sp - m12;
    float sq = mu1 * mu1 + mu2 * mu2;
    return ((2.f * m12 + C1F) * (2.f * sigma + C2F)) / ((sq + C1F) * (sq + C2F));
}

// Each thread: 4 cols (one float4 group) x 4 output rows, all in registers.
// Block: 256 threads = 128 col-groups x 2 row-chunks -> covers 512 wide x 8 rows.
// Grid: (64 row-blocks, 32 images) = 2048 blocks -> 8 blocks/CU.
// launch_bounds(256,4): VGPR cap 128 (the HW quantum below spill territory).
// NOTE: (256,5) forces VGPR<=64 -> 40+ floats spill to scratch, 490 MB of
// scratch writes, 2.5x slowdown (measured round 1). Do not raise waves/EU.
__global__ __launch_bounds__(256, 4)
void ssim_fused_kernel(const float* __restrict__ A, const float* __restrict__ B,
                       float* __restrict__ out, float inv_total) {
    __shared__ float wpart[4];

    const int tid = threadIdx.x;
    const int g = tid & (NG - 1);        // col-group 0..127
    const int rchunk = tid >> 7;         // 0..1 (wave-uniform: waves 0,1 vs 2,3)
    const int img = blockIdx.y;
    const int ybase = blockIdx.x * (2 * T) + rchunk * T;   // first output row

    // Gaussian weights (sigma=1.5, K=11) — same fp32 recipe that matched np
    // bit-exactly in earlier rounds. Forced into SGPRs (wave-uniform).
    float w[KW];
    {
        float s = 0.f;
#pragma unroll
        for (int i = 0; i < KW; ++i) {
            float d = (float)(i - RAD);
            w[i] = expf(-(d * d) / 4.5f);
            s += w[i];
        }
        float inv = 1.0f / s;
#pragma unroll
        for (int i = 0; i < KW; ++i) {
            w[i] *= inv;
            w[i] = __int_as_float(__builtin_amdgcn_readfirstlane(__float_as_int(w[i])));
        }
    }

    const float* __restrict__ Ai = A + (size_t)img * IMG_H * IMG_W;
    const float* __restrict__ Bi = B + (size_t)img * IMG_H * IMG_W;

    float4 accA[T], accB[T], accP[T];
#pragma unroll
    for (int o = 0; o < T; ++o) {
        accA[o] = make_float4(0.f, 0.f, 0.f, 0.f);
        accB[o] = accA[o];
        accP[o] = accA[o];
    }

    // Walk T + 2*RAD = 14 input rows; h-conv each, scatter into vertical accs.
#pragma unroll
    for (int i = 0; i < T + 2 * RAD; ++i) {
        int gy = ybase + i - RAD;
        if (gy >= 0 && gy < IMG_H) {     // wave-uniform branch (cheap s_cbranch)
            const float* rowA = Ai + (size_t)gy * IMG_W;
            const float* rowB = Bi + (size_t)gy * IMG_W;

            // Need cols 4g-5 .. 4g+8 (14 floats): 1 scalar + 3 float4 + 1 scalar.
            // fa[j] = col (4g-5+j).
            float fa[14], fb[14];
            {
                int c = 4 * g - 5;
                bool v = (c >= 0);
                fa[0] = v ? rowA[c] : 0.f;
                fb[0] = v ? rowB[c] : 0.f;
            }
            {   // group g-1: cols 4g-4..4g-1 (invalid only for g==0)
                float4 va = make_float4(0.f, 0.f, 0.f, 0.f);
                float4 vb = va;
                if (g >= 1) {
                    va = *(const float4*)(rowA + 4 * (g - 1));
                    vb = *(const float4*)(rowB + 4 * (g - 1));
                }
                fa[1] = va.x; fa[2] = va.y; fa[3] = va.z; fa[4] = va.w;
                fb[1] = vb.x; fb[2] = vb.y; fb[3] = vb.z; fb[4] = vb.w;
            }
            {   // group g: always valid
                float4 va = *(const float4*)(rowA + 4 * g);
                float4 vb = *(const float4*)(rowB + 4 * g);
                fa[5] = va.x; fa[6] = va.y; fa[7] = va.z; fa[8] = va.w;
                fb[5] = vb.x; fb[6] = vb.y; fb[7] = vb.z; fb[8] = vb.w;
            }
            {   // group g+1: cols 4g+4..4g+7 (invalid only for g==127)
                float4 va = make_float4(0.f, 0.f, 0.f, 0.f);
                float4 vb = va;
                if (g <= NG - 2) {
                    va = *(const float4*)(rowA + 4 * (g + 1));
                    vb = *(const float4*)(rowB + 4 * (g + 1));
                }
                fa[9]  = va.x; fa[10] = va.y; fa[11] = va.z; fa[12] = va.w;
                fb[9]  = vb.x; fb[10] = vb.y; fb[11] = vb.z; fb[12] = vb.w;
            }
            {
                int c = 4 * g + 8;
                bool v = (c < IMG_W);
                fa[13] = v ? rowA[c] : 0.f;
                fb[13] = v ? rowB[c] : 0.f;
            }

            // Shared A*B products (CSE across the 4 output columns).
            float p[14];
#pragma unroll
            for (int j = 0; j < 14; ++j) p[j] = fa[j] * fb[j];

            // Horizontal 11-tap conv: output col c uses index c+k, k=0..10.
            float4 hA = make_float4(0.f, 0.f, 0.f, 0.f);
            float4 hB = hA, hP = hA;
#pragma unroll
            for (int k = 0; k < KW; ++k) {
                float wk = w[k];
                hA.x += wk * fa[k];     hA.y += wk * fa[k + 1];
                hA.z += wk * fa[k + 2]; hA.w += wk * fa[k + 3];
                hB.x += wk * fb[k];     hB.y += wk * fb[k + 1];
                hB.z += wk * fb[k + 2]; hB.w += wk * fb[k + 3];
                hP.x += wk * p[k];      hP.y += wk * p[k + 1];
                hP.z += wk * p[k + 2];  hP.w += wk * p[k + 3];
            }

            // Vertical scatter: output o gets weight w[i-o] when 0 <= i-o <= 10.
#pragma unroll
            for (int o = 0; o < T; ++o) {
                if (i - o >= 0 && i - o < KW) {
                    float wk = w[i - o];
                    accA[o].x += wk * hA.x; accA[o].y += wk * hA.y;
                    accA[o].z += wk * hA.z; accA[o].w += wk * hA.w;
                    accB[o].x += wk * hB.x; accB[o].y += wk * hB.y;
                    accB[o].z += wk * hB.z; accB[o].w += wk * hB.w;
                    accP[o].x += wk * hP.x; accP[o].y += wk * hP.y;
                    accP[o].z += wk * hP.z; accP[o].w += wk * hP.w;
                }
            }
        }
    }

    // SSIM formula per pixel + per-thread accumulate (16 px/thread).
    float acc = 0.f;
#pragma unroll
    for (int o = 0; o < T; ++o) {
        acc += ssim_px(accA[o].x, accB[o].x, accP[o].x);
        acc += ssim_px(accA[o].y, accB[o].y, accP[o].y);
        acc += ssim_px(accA[o].z, accB[o].z, accP[o].z);
        acc += ssim_px(accA[o].w, accB[o].w, accP[o].w);
    }

    // Reduce: wave shuffle -> LDS -> one atomic per block.
#pragma unroll
    for (int off = 32; off > 0; off >>= 1)
        acc += __shfl_down(acc, off, 64);
    int wid = tid >> 6;
    int lane = tid & 63;
    if (lane == 0) wpart[wid] = acc;
    __syncthreads();
    if (tid == 0) {
        float s = (wpart[0] + wpart[1]) + (wpart[2] + wpart[3]);
        atomicAdd(out, s * inv_total);
    }
}

extern "C" void kernel_launch(void* const* d_in, const int* in_sizes, int n_in,
                              void* d_out, int out_size, void* d_ws, size_t ws_size,
                              hipStream_t stream) {
    const float* A = (const float*)d_in[0];
    const float* B = (const float*)d_in[1];
    float* out = (float*)d_out;

    const int total = in_sizes[0];                 // 32*1*512*512
    const int nimg = total / (IMG_H * IMG_W);      // 32

    hipMemsetAsync(d_out, 0, sizeof(float), stream);

    dim3 grid(IMG_H / (2 * T), nimg, 1);           // (64, 32)
    ssim_fused_kernel<<<grid, 256, 0, stream>>>(A, B, out, 1.0f / (float)total);
}